// Round 6
// baseline (162462.976 us; speedup 1.0000x reference)
//
#include <hip/hip_runtime.h>
#include <math.h>

// ---------------- problem constants ----------------
#define BATCH 256
#define TLEN  519          // W + MAXLAG
#define WIN   512
#define HID   256
#define PRED  24
#define NS    100
#define NLAG  7
#define GROWS (BATCH * NS) // 25600 decoder rows

// ---------------- workspace layout (float/uint offsets) ----------------
#define OFF_SCALED 0
#define OFF_LOC    132864
#define OFF_SCALE  133120
#define OFF_WIH0   133376   // fp32 [f][j][q], f<7  (encoder lag weights)
#define OFF_WHH0H  140544   // half2 [p][j][q], p<128 (encoder)
#define OFF_WCAT1H 271616   // half2 [p][j][q], p<256 (encoder, ih1|hh1)
#define OFF_B0     533760   // fp32 combined b_ih0+b_hh0, [j][q]
#define OFF_B1     534784
#define OFF_BN0    535808   // fp32 bias by MFMA col n (layer0)
#define OFF_BN1    536832
#define OFF_F0     537856   // fp16 B-fragments layer0: 9 ks x 64 nt x 64 lane x 8
#define OFF_F1     685312   // fp16 B-fragments layer1: 16 ks x 64 nt x 64 lane x 8
#define OFF_EH0    947456   // encoder final states fp32 [b][j]
#define OFF_EC0    1012992
#define OFF_EH1    1078528
#define OFF_EC1    1144064
#define OFF_ACC    1209600  // sample accumulators [b][p]
// ---- encoder cross-block sync boards ----
#define OFF_FLAGS  1215744  // ints: flag0[256], flag1[256], fh0[256], fh1[256]
#define OFF_FLG0   (OFF_FLAGS + 0)
#define OFF_FLG1   (OFF_FLAGS + 256)
#define OFF_FH0    (OFF_FLAGS + 512)
#define OFF_FH1    (OFF_FLAGS + 768)
#define OFF_HB0    1216768  // uints 32768: h0 board halves [g][sig][row][64]
#define OFF_HB1    1249536  // uints 32768: h1 board
#define OFF_PART0  1282304  // floats 1048576: [g][src][row][unit] float4
#define OFF_PART1  2330880  // floats 1048576
#define WS_FLOATS  3379456  // 13.5 MB

// ---------------- helpers ----------------
typedef _Float16 h2_t  __attribute__((ext_vector_type(2)));
typedef _Float16 half8 __attribute__((ext_vector_type(8)));
typedef float    f32x4 __attribute__((ext_vector_type(4)));

__device__ __forceinline__ float sigm(float x) { return 1.0f / (1.0f + __expf(-x)); }
__device__ __forceinline__ float ftanh(float x) {
    float e = __expf(2.0f * x);
    return 1.0f - 2.0f / (e + 1.0f);
}
__device__ __forceinline__ float softplus(float x) {
    return (x > 15.0f) ? x : log1pf(__expf(x));
}
__device__ __forceinline__ void fma4(float4& a, const float4 w, const float x) {
    a.x = fmaf(w.x, x, a.x);
    a.y = fmaf(w.y, x, a.y);
    a.z = fmaf(w.z, x, a.z);
    a.w = fmaf(w.w, x, a.w);
}
__device__ __forceinline__ float dot2(unsigned int h, unsigned int w, float acc) {
    return __builtin_amdgcn_fdot2(__builtin_bit_cast(h2_t, h),
                                  __builtin_bit_cast(h2_t, w), acc, false);
}
__device__ __forceinline__ void dot2x4(float4& a, const unsigned int h, const uint4 w) {
    a.x = dot2(h, w.x, a.x);
    a.y = dot2(h, w.y, a.y);
    a.z = dot2(h, w.z, a.z);
    a.w = dot2(h, w.w, a.w);
}
__device__ __forceinline__ unsigned int packh2(float a, float b) {
    h2_t h;
    h.x = (_Float16)a;
    h.y = (_Float16)b;
    return __builtin_bit_cast(unsigned int, h);
}
__device__ __forceinline__ unsigned short hbits(float v) {
    return __builtin_bit_cast(unsigned short, (_Float16)v);
}
__device__ __forceinline__ void spin_ge(int* p, int target) {
    while (__hip_atomic_load(p, __ATOMIC_ACQUIRE, __HIP_MEMORY_SCOPE_AGENT) < target)
        __builtin_amdgcn_s_sleep(4);
}
__device__ __forceinline__ void flag_set(int* p, int v) {
    __hip_atomic_store(p, v, __ATOMIC_RELEASE, __HIP_MEMORY_SCOPE_AGENT);
}
__device__ __forceinline__ void add4(float4& a, const float4 b) {
    a.x += b.x; a.y += b.y; a.z += b.z; a.w += b.w;
}

// ---------------- kernel 1: repack weights ----------------
__global__ __launch_bounds__(256) void prep_weights(
    const float* __restrict__ w_ih0, const float* __restrict__ w_hh0,
    const float* __restrict__ b_ih0, const float* __restrict__ b_hh0,
    const float* __restrict__ w_ih1, const float* __restrict__ w_hh1,
    const float* __restrict__ b_ih1, const float* __restrict__ b_hh1,
    float* __restrict__ ws) {
    int id = blockIdx.x * blockDim.x + threadIdx.x;   // grid covers 262144
    unsigned int* wsu = (unsigned int*)ws;
    // ---- encoder layouts ----
    {
        int g4 = id & 1023;
        int jj = g4 >> 2, q = g4 & 3;
        int grow = q * HID + jj;
        int p = id >> 10;
        int k0 = 2 * p;
        float v0, v1;
        if (k0 < 256) { v0 = w_ih1[grow * HID + k0];       v1 = w_ih1[grow * HID + k0 + 1]; }
        else          { v0 = w_hh1[grow * HID + k0 - 256]; v1 = w_hh1[grow * HID + k0 - 255]; }
        wsu[OFF_WCAT1H + id] = packh2(v0, v1);
        if (id < 131072) {
            wsu[OFF_WHH0H + id] = packh2(w_hh0[grow * HID + 2 * p], w_hh0[grow * HID + 2 * p + 1]);
        }
        if (id < 7168) {
            int f = id >> 10;
            ws[OFF_WIH0 + id] = w_ih0[grow * NLAG + f];
        }
        if (id < 1024) {
            ws[OFF_B0 + id] = b_ih0[grow] + b_hh0[grow];
            ws[OFF_B1 + id] = b_ih1[grow] + b_hh1[grow];
        }
    }
    // ---- decoder biases by MFMA col ----
    if (id < 2048) {
        int n = id & 1023;
        int w = n >> 8, u = (n >> 2) & 63, q = n & 3;
        int grow = q * HID + w * 64 + u;
        if (id < 1024) ws[OFF_BN0 + n] = b_ih0[grow] + b_hh0[grow];
        else           ws[OFF_BN1 + n] = b_ih1[grow] + b_hh1[grow];
    }
    // ---- F0 fragments: 9 ks (ks0 = lag block) ----
    if (id < 36864) {
        int ks = id / 4096, rem = id % 4096, nt = rem >> 6, l = rem & 63;
        int n = nt * 16 + (l & 15);
        int w = n >> 8, u = (n >> 2) & 63, q = n & 3;
        int grow = q * HID + w * 64 + u;
        int kbase = (l >> 4) * 8;
        unsigned short h8[8];
        #pragma unroll
        for (int i = 0; i < 8; ++i) {
            float v;
            if (ks == 0) { int k = kbase + i; v = (k < NLAG) ? w_ih0[grow * NLAG + k] : 0.0f; }
            else         { int kk = (ks - 1) * 32 + kbase + i; v = w_hh0[grow * HID + kk]; }
            h8[i] = hbits(v);
        }
        uint4 o;
        o.x = (unsigned int)h8[0] | ((unsigned int)h8[1] << 16);
        o.y = (unsigned int)h8[2] | ((unsigned int)h8[3] << 16);
        o.z = (unsigned int)h8[4] | ((unsigned int)h8[5] << 16);
        o.w = (unsigned int)h8[6] | ((unsigned int)h8[7] << 16);
        ((uint4*)(ws + OFF_F0))[id] = o;
    }
    // ---- F1 fragments: 16 ks ----
    if (id < 65536) {
        int ks = id >> 12, rem = id & 4095, nt = rem >> 6, l = rem & 63;
        int n = nt * 16 + (l & 15);
        int w = n >> 8, u = (n >> 2) & 63, q = n & 3;
        int grow = q * HID + w * 64 + u;
        int kbase = (l >> 4) * 8;
        unsigned short h8[8];
        #pragma unroll
        for (int i = 0; i < 8; ++i) {
            int kk = ks * 32 + kbase + i;
            float v = (kk < 256) ? w_ih1[grow * HID + kk] : w_hh1[grow * HID + kk - 256];
            h8[i] = hbits(v);
        }
        uint4 o;
        o.x = (unsigned int)h8[0] | ((unsigned int)h8[1] << 16);
        o.y = (unsigned int)h8[2] | ((unsigned int)h8[3] << 16);
        o.z = (unsigned int)h8[4] | ((unsigned int)h8[5] << 16);
        o.w = (unsigned int)h8[6] | ((unsigned int)h8[7] << 16);
        ((uint4*)(ws + OFF_F1))[id] = o;
    }
}

// ---------------- kernel 2: normalize + zero accumulators/flags ----------------
__global__ __launch_bounds__(256) void prep_norm(const float* __restrict__ x,
                                                 float* __restrict__ ws) {
    const int b = blockIdx.x, j = threadIdx.x;
    const int gid = b * 256 + j;
    if (gid < 1024) ((int*)(ws + OFF_FLAGS))[gid] = 0;          // sync flags
    if (gid < 32768) ((unsigned int*)ws)[OFF_HB1 + gid] = 0u;   // h1(-1) = 0
    const float* row = x + b * TLEN;
    float s = 0.0f, s2 = 0.0f;
    for (int t = j; t < WIN; t += 256) {
        float v = row[NLAG + t];
        s += v;
        s2 = fmaf(v, v, s2);
    }
    #pragma unroll
    for (int off = 32; off > 0; off >>= 1) {
        s  += __shfl_down(s, off, 64);
        s2 += __shfl_down(s2, off, 64);
    }
    __shared__ float rs[4], rs2[4];
    __shared__ float sh_loc, sh_scale;
    int wave = j >> 6, lane = j & 63;
    if (lane == 0) { rs[wave] = s; rs2[wave] = s2; }
    __syncthreads();
    if (j == 0) {
        float S = rs[0] + rs[1] + rs[2] + rs[3];
        float S2 = rs2[0] + rs2[1] + rs2[2] + rs2[3];
        float mean = S * (1.0f / WIN);
        float var = S2 * (1.0f / WIN) - mean * mean;
        float sd = sqrtf(fmaxf(var, 0.0f));
        if (sd < 1e-10f) sd = 1.0f;
        sh_loc = mean; sh_scale = sd;
        ws[OFF_LOC + b] = mean;
        ws[OFF_SCALE + b] = sd;
    }
    __syncthreads();
    float loc = sh_loc, inv = 1.0f / sh_scale;
    for (int t = j; t < TLEN; t += 256) {
        ws[OFF_SCALED + b * TLEN + t] = (row[t] - loc) * inv;
    }
    if (j < PRED) ws[OFF_ACC + b * PRED + j] = 0.0f;
}

// ---------------- kernel 3: encoder, 4-way cross-block k-split ----------------
// 256 blocks x 1024 threads (all CUs). group g = blockIdx&63 owns rows 4g..4g+3;
// slice s = blockIdx>>6 streams 1/4 of the weights (384 KB/step/CU) and
// finalizes units [64s,64s+64). Partial gate sums + h-chunks exchanged via L2
// boards with monotonic release/acquire flag counters (no double-buffering
// needed: flag chain serializes all WAR hazards; 256 blocks all co-resident).
#define ENC_T 1024
__global__ __launch_bounds__(ENC_T) void encoder_kernel(float* ws) {
    const int tid = threadIdx.x;
    const int j = tid & 255;        // unit (partial phase)
    const int q = tid >> 8;         // k-sub (0..3)
    const int g = blockIdx.x & 63;  // row group
    const int s = blockIdx.x >> 6;  // weight slice

    __shared__ float4 pgs[4][4][256];     // [row][sub][unit] 64 KB
    __shared__ float4 wlagS[NLAG * 64];   // own-unit lag weights 7 KB
    __shared__ unsigned int h0L[32 * 4];  // own h0 pairs [pairloc][row]
    __shared__ unsigned int hin[64 * 4];  // L1 input pairs [pairloc][row]
    __shared__ float c0own[4][64], c1own[4][64];
    __shared__ float xs[4][NLAG];

    const uint4* W0 = (const uint4*)((const unsigned int*)ws + OFF_WHH0H);
    const uint4* W1 = (const uint4*)((const unsigned int*)ws + OFF_WCAT1H);
    const float4* wihv = (const float4*)(ws + OFF_WIH0);
    float4* part0v = (float4*)(ws + OFF_PART0);
    float4* part1v = (float4*)(ws + OFF_PART1);
    _Float16* hb0 = (_Float16*)((unsigned int*)ws + OFF_HB0);
    _Float16* hb1 = (_Float16*)((unsigned int*)ws + OFF_HB1);
    const unsigned int* hb0u = (const unsigned int*)ws + OFF_HB0;
    const unsigned int* hb1u = (const unsigned int*)ws + OFF_HB1;
    int* flg0 = (int*)(ws + OFF_FLG0);
    int* flg1 = (int*)(ws + OFF_FLG1);
    int* fh0f = (int*)(ws + OFF_FH0);
    int* fh1f = (int*)(ws + OFF_FH1);

    // preamble
    if (tid < NLAG * 64) wlagS[tid] = wihv[(tid >> 6) * 256 + 64 * s + (tid & 63)];
    if (tid < 128) h0L[tid] = 0u;
    if (tid < 256) { ((float*)c0own)[tid] = 0.0f; ((float*)c1own)[tid] = 0.0f; }
    float4 bO0 = {0, 0, 0, 0}, bO1 = {0, 0, 0, 0};
    if (tid < 256) {
        bO0 = ((const float4*)(ws + OFF_B0))[64 * s + (tid & 63)];
        bO1 = ((const float4*)(ws + OFF_B1))[64 * s + (tid & 63)];
    }
    const int fb = g * 4;
    __syncthreads();

    for (int t = 0; t < WIN; ++t) {
        // lag inputs for this step
        if (tid < 4 * NLAG) {
            int r = tid / NLAG, f = tid % NLAG;
            xs[r][f] = ws[OFF_SCALED + (4 * g + r) * TLEN + t + 6 - f];
        }
        // ---- phase A: L0 partials over this slice+sub's 8 k-pairs ----
        {
            float4 a0 = {0,0,0,0}, a1 = {0,0,0,0}, a2 = {0,0,0,0}, a3 = {0,0,0,0};
            const uint4* Wp = W0 + (s * 32 + q * 8) * 256 + j;
            #pragma unroll 2
            for (int i = 0; i < 8; ++i) {
                uint4 w = Wp[i * 256];
                uint4 h4 = *(const uint4*)&h0L[(q * 8 + i) * 4];
                dot2x4(a0, h4.x, w);
                dot2x4(a1, h4.y, w);
                dot2x4(a2, h4.z, w);
                dot2x4(a3, h4.w, w);
            }
            pgs[0][q][j] = a0; pgs[1][q][j] = a1; pgs[2][q][j] = a2; pgs[3][q][j] = a3;
        }
        __syncthreads();
        {   // block total partial (row = q) -> board
            float4 t4 = pgs[q][0][j];
            add4(t4, pgs[q][1][j]); add4(t4, pgs[q][2][j]); add4(t4, pgs[q][3][j]);
            part0v[((fb + s) * 4 + q) * 256 + j] = t4;
        }
        __threadfence();
        __syncthreads();
        if (tid == 0) flag_set(&flg0[fb + s], t + 1);
        // ---- phase B: finalize own 64 units ----
        if (tid == 0) {
            spin_ge(&flg0[fb + ((s + 1) & 3)], t + 1);
            spin_ge(&flg0[fb + ((s + 2) & 3)], t + 1);
            spin_ge(&flg0[fb + ((s + 3) & 3)], t + 1);
        }
        __syncthreads();
        if (tid < 256) {
            int u = tid & 63, row = tid >> 6;
            int unit = 64 * s + u;
            float4 a = bO0;
            #pragma unroll
            for (int f = 0; f < NLAG; ++f) fma4(a, wlagS[f * 64 + u], xs[row][f]);
            add4(a, pgs[row][0][unit]); add4(a, pgs[row][1][unit]);
            add4(a, pgs[row][2][unit]); add4(a, pgs[row][3][unit]);
            #pragma unroll
            for (int o = 1; o < 4; ++o) {
                int sp = (s + o) & 3;
                add4(a, part0v[((fb + sp) * 4 + row) * 256 + unit]);
            }
            float c = sigm(a.y) * c0own[row][u] + sigm(a.x) * ftanh(a.z);
            c0own[row][u] = c;
            float hv = sigm(a.w) * ftanh(c);
            _Float16 hh = (_Float16)hv;
            ((_Float16*)h0L)[((u >> 1) * 4 + row) * 2 + (u & 1)] = hh;
            hb0[((fb + s) * 4 + row) * 64 + u] = hh;
        }
        __threadfence();
        __syncthreads();
        if (tid == 0) flag_set(&fh0f[fb + s], t + 1);
        // ---- phase C: L1 partials ----
        if (tid == 0) {
            if (s == 0)      { spin_ge(&fh0f[fb + 1], t + 1); }
            else if (s == 1) { spin_ge(&fh0f[fb + 2], t + 1); spin_ge(&fh0f[fb + 3], t + 1); }
            else if (s == 2) { spin_ge(&fh1f[fb + 0], t);     spin_ge(&fh1f[fb + 1], t); }
            else             { spin_ge(&fh1f[fb + 2], t); }
        }
        __syncthreads();
        if (tid < 256) {   // load this slice's L1 input pairs (h0 or h1(t-1))
            int pl = tid >> 2, row = tid & 3;
            int unit = (s & 1) * 128 + pl * 2;
            int sig = unit >> 6, off = unit & 63;
            const unsigned int* board = (s < 2) ? hb0u : hb1u;
            hin[pl * 4 + row] = board[((fb + sig) * 4 + row) * 32 + (off >> 1)];
        }
        __syncthreads();
        {
            float4 a0 = {0,0,0,0}, a1 = {0,0,0,0}, a2 = {0,0,0,0}, a3 = {0,0,0,0};
            const uint4* Wp = W1 + (s * 64 + q * 16) * 256 + j;
            #pragma unroll 4
            for (int i = 0; i < 16; ++i) {
                uint4 w = Wp[i * 256];
                uint4 h4 = *(const uint4*)&hin[(q * 16 + i) * 4];
                dot2x4(a0, h4.x, w);
                dot2x4(a1, h4.y, w);
                dot2x4(a2, h4.z, w);
                dot2x4(a3, h4.w, w);
            }
            pgs[0][q][j] = a0; pgs[1][q][j] = a1; pgs[2][q][j] = a2; pgs[3][q][j] = a3;
        }
        __syncthreads();
        {
            float4 t4 = pgs[q][0][j];
            add4(t4, pgs[q][1][j]); add4(t4, pgs[q][2][j]); add4(t4, pgs[q][3][j]);
            part1v[((fb + s) * 4 + q) * 256 + j] = t4;
        }
        __threadfence();
        __syncthreads();
        if (tid == 0) flag_set(&flg1[fb + s], t + 1);
        // ---- phase D: finalize h1 own units ----
        if (tid == 0) {
            spin_ge(&flg1[fb + ((s + 1) & 3)], t + 1);
            spin_ge(&flg1[fb + ((s + 2) & 3)], t + 1);
            spin_ge(&flg1[fb + ((s + 3) & 3)], t + 1);
        }
        __syncthreads();
        if (tid < 256) {
            int u = tid & 63, row = tid >> 6;
            int unit = 64 * s + u;
            float4 a = bO1;
            add4(a, pgs[row][0][unit]); add4(a, pgs[row][1][unit]);
            add4(a, pgs[row][2][unit]); add4(a, pgs[row][3][unit]);
            #pragma unroll
            for (int o = 1; o < 4; ++o) {
                int sp = (s + o) & 3;
                add4(a, part1v[((fb + sp) * 4 + row) * 256 + unit]);
            }
            float c = sigm(a.y) * c1own[row][u] + sigm(a.x) * ftanh(a.z);
            c1own[row][u] = c;
            float hv = sigm(a.w) * ftanh(c);
            hb1[((fb + s) * 4 + row) * 64 + u] = (_Float16)hv;
        }
        __threadfence();
        __syncthreads();
        if (tid == 0) flag_set(&fh1f[fb + s], t + 1);
    }
    // final states -> decoder format
    if (tid < 256) {
        int u = tid & 63, row = tid >> 6;
        int b = 4 * g + row, unit = 64 * s + u;
        ws[OFF_EH0 + b * HID + unit] = (float)((_Float16*)h0L)[((u >> 1) * 4 + row) * 2 + (u & 1)];
        ws[OFF_EC0 + b * HID + unit] = c0own[row][u];
        ws[OFF_EH1 + b * HID + unit] = (float)hb1[((fb + s) * 4 + row) * 64 + u];
        ws[OFF_EC1 + b * HID + unit] = c1own[row][u];
    }
}

// ---------------- kernel 4: MFMA decoder (r4 structure, RDEC=32) ----------------
#define RDEC 32
__global__ __launch_bounds__(256, 2) void decoder_kernel(
    const float* __restrict__ wsr,
    const float* __restrict__ w_mu, const float* __restrict__ b_mu,
    const float* __restrict__ w_sigma, const float* __restrict__ b_sigma,
    const float* __restrict__ eps, float* __restrict__ wsw) {
    const int j = threadIdx.x, lane = j & 63, wv = j >> 6;
    const int gr0 = blockIdx.x * RDEC;
    const int m16 = lane & 15, q16 = lane >> 4;
    __shared__ _Float16 hA[2][RDEC][264];   // [layer][row][unit], pad to 264
    __shared__ _Float16 xlag[RDEC][32];     // lag A-tile (k 0..6 live, rest 0)
    __shared__ float scr[4][16][68];        // per-wave D transpose scratch

    const uint4* F0 = (const uint4*)(wsr + OFF_F0);
    const uint4* F1 = (const uint4*)(wsr + OFF_F1);
    const float* bn0 = wsr + OFF_BN0;
    const float* bn1 = wsr + OFF_BN1;

    float c0r[8][4], c1r[8][4];
    for (int r = 0; r < RDEC; ++r) {
        int b = (gr0 + r) / NS;
        hA[0][r][j] = (_Float16)wsr[OFF_EH0 + b * HID + j];
        hA[1][r][j] = (_Float16)wsr[OFF_EH1 + b * HID + j];
    }
    { int r = j >> 3, p = j & 7;
      hA[0][r][256 + p] = (_Float16)0.0f; hA[1][r][256 + p] = (_Float16)0.0f; }
    #pragma unroll
    for (int it = 0; it < 4; ++it) {
        int idx = j + 256 * it;
        int r = idx >> 5, k = idx & 31;
        int b = (gr0 + r) / NS;
        xlag[r][k] = (k < NLAG) ? (_Float16)wsr[OFF_SCALED + b * TLEN + WIN + 6 - k]
                                : (_Float16)0.0f;
    }
    #pragma unroll
    for (int Q = 0; Q < 4; ++Q)
        #pragma unroll
        for (int mt = 0; mt < 2; ++mt) {
            int t2 = Q * 2 + mt;
            int b = (gr0 + mt * 16 + m16) / NS;
            #pragma unroll
            for (int i = 0; i < 4; ++i) {
                int jg = wv * 64 + Q * 16 + q16 * 4 + i;
                c0r[t2][i] = wsr[OFF_EC0 + b * HID + jg];
                c1r[t2][i] = wsr[OFF_EC1 + b * HID + jg];
            }
        }
    __syncthreads();

    float* accg = wsw + OFF_ACC;
    for (int st = 0; st < PRED; ++st) {
        uint2 hnew[8];
        // ================= layer 0 =================
        #pragma unroll 1
        for (int Q = 0; Q < 4; ++Q) {
            f32x4 acc[2][4];
            #pragma unroll
            for (int t = 0; t < 4; ++t) {
                float bb = bn0[wv * 256 + Q * 64 + t * 16 + m16];
                acc[0][t] = (f32x4){bb, bb, bb, bb};
                acc[1][t] = acc[0][t];
            }
            #pragma unroll
            for (int ks = 0; ks < 9; ++ks) {
                uint4 bw[4];
                #pragma unroll
                for (int t = 0; t < 4; ++t)
                    bw[t] = F0[(ks * 64 + wv * 16 + Q * 4 + t) * 64 + lane];
                #pragma unroll
                for (int mt = 0; mt < 2; ++mt) {
                    const _Float16* ap = (ks == 0)
                        ? &xlag[mt * 16 + m16][q16 * 8]
                        : &hA[0][mt * 16 + m16][(ks - 1) * 32 + q16 * 8];
                    half8 av = *(const half8*)ap;
                    #pragma unroll
                    for (int t = 0; t < 4; ++t)
                        acc[mt][t] = __builtin_amdgcn_mfma_f32_16x16x32_f16(
                            av, __builtin_bit_cast(half8, bw[t]), acc[mt][t], 0, 0, 0);
                }
            }
            #pragma unroll
            for (int mt = 0; mt < 2; ++mt) {
                #pragma unroll
                for (int t = 0; t < 4; ++t)
                    #pragma unroll
                    for (int rg = 0; rg < 4; ++rg)
                        scr[wv][q16 * 4 + rg][t * 16 + m16] = acc[mt][t][rg];
                __builtin_amdgcn_wave_barrier();
                int t2 = Q * 2 + mt;
                float hv[4];
                #pragma unroll
                for (int i = 0; i < 4; ++i) {
                    float4 g = *(const float4*)&scr[wv][m16][(q16 * 4 + i) * 4];
                    float c = sigm(g.y) * c0r[t2][i] + sigm(g.x) * ftanh(g.z);
                    c0r[t2][i] = c;
                    hv[i] = sigm(g.w) * ftanh(c);
                }
                __builtin_amdgcn_wave_barrier();
                hnew[t2] = make_uint2(packh2(hv[0], hv[1]), packh2(hv[2], hv[3]));
            }
        }
        __syncthreads();   // all L0 reads of hA[0]/xlag done
        #pragma unroll
        for (int Q = 0; Q < 4; ++Q)
            #pragma unroll
            for (int mt = 0; mt < 2; ++mt)
                *(uint2*)&hA[0][mt * 16 + m16][wv * 64 + Q * 16 + q16 * 4] = hnew[Q * 2 + mt];
        __syncthreads();   // hA[0] now h0(t)
        // ================= layer 1 =================
        #pragma unroll 1
        for (int Q = 0; Q < 4; ++Q) {
            f32x4 acc[2][4];
            #pragma unroll
            for (int t = 0; t < 4; ++t) {
                float bb = bn1[wv * 256 + Q * 64 + t * 16 + m16];
                acc[0][t] = (f32x4){bb, bb, bb, bb};
                acc[1][t] = acc[0][t];
            }
            #pragma unroll
            for (int ks = 0; ks < 16; ++ks) {
                uint4 bw[4];
                #pragma unroll
                for (int t = 0; t < 4; ++t)
                    bw[t] = F1[(ks * 64 + wv * 16 + Q * 4 + t) * 64 + lane];
                #pragma unroll
                for (int mt = 0; mt < 2; ++mt) {
                    const _Float16* ap = (ks < 8)
                        ? &hA[0][mt * 16 + m16][ks * 32 + q16 * 8]
                        : &hA[1][mt * 16 + m16][(ks - 8) * 32 + q16 * 8];
                    half8 av = *(const half8*)ap;
                    #pragma unroll
                    for (int t = 0; t < 4; ++t)
                        acc[mt][t] = __builtin_amdgcn_mfma_f32_16x16x32_f16(
                            av, __builtin_bit_cast(half8, bw[t]), acc[mt][t], 0, 0, 0);
                }
            }
            #pragma unroll
            for (int mt = 0; mt < 2; ++mt) {
                #pragma unroll
                for (int t = 0; t < 4; ++t)
                    #pragma unroll
                    for (int rg = 0; rg < 4; ++rg)
                        scr[wv][q16 * 4 + rg][t * 16 + m16] = acc[mt][t][rg];
                __builtin_amdgcn_wave_barrier();
                int t2 = Q * 2 + mt;
                float hv[4];
                #pragma unroll
                for (int i = 0; i < 4; ++i) {
                    float4 g = *(const float4*)&scr[wv][m16][(q16 * 4 + i) * 4];
                    float c = sigm(g.y) * c1r[t2][i] + sigm(g.x) * ftanh(g.z);
                    c1r[t2][i] = c;
                    hv[i] = sigm(g.w) * ftanh(c);
                }
                __builtin_amdgcn_wave_barrier();
                hnew[t2] = make_uint2(packh2(hv[0], hv[1]), packh2(hv[2], hv[3]));
            }
        }
        __syncthreads();   // all L1 reads of hA done
        #pragma unroll
        for (int Q = 0; Q < 4; ++Q)
            #pragma unroll
            for (int mt = 0; mt < 2; ++mt)
                *(uint2*)&hA[1][mt * 16 + m16][wv * 64 + Q * 16 + q16 * 4] = hnew[Q * 2 + mt];
        __syncthreads();   // hA[1] now h1(t)
        // ================= mu / sigma / sample =================
        #pragma unroll 1
        for (int it = 0; it < 8; ++it) {
            int rr = wv + it * 4;
            uint2 hu = *(const uint2*)&hA[1][rr][lane * 4];
            h2_t p0 = __builtin_bit_cast(h2_t, hu.x);
            h2_t p1 = __builtin_bit_cast(h2_t, hu.y);
            float4 wm = *(const float4*)&w_mu[lane * 4];
            float4 wsg = *(const float4*)&w_sigma[lane * 4];
            float h0f = (float)p0.x, h1f = (float)p0.y, h2f = (float)p1.x, h3f = (float)p1.y;
            float sm = h0f * wm.x + h1f * wm.y + h2f * wm.z + h3f * wm.w;
            float ss = h0f * wsg.x + h1f * wsg.y + h2f * wsg.z + h3f * wsg.w;
            #pragma unroll
            for (int off = 32; off > 0; off >>= 1) {
                sm += __shfl_down(sm, off, 64);
                ss += __shfl_down(ss, off, 64);
            }
            if (lane == 0) {
                float mu = sm + b_mu[0];
                float sg = softplus(ss + b_sigma[0]);
                int gr = gr0 + rr;
                float smp = fmaf(sg, eps[st * GROWS + gr], mu);
                atomicAdd(&accg[(gr / NS) * PRED + st], smp);
                #pragma unroll
                for (int f = NLAG - 1; f >= 1; --f) xlag[rr][f] = xlag[rr][f - 1];
                xlag[rr][0] = (_Float16)smp;
            }
        }
        __syncthreads();   // xlag(t+1) visible
    }
}

// ---------------- kernel 5: finalize ----------------
__global__ __launch_bounds__(256) void finalize_kernel(const float* __restrict__ ws,
                                                       float* __restrict__ out) {
    int i = blockIdx.x * blockDim.x + threadIdx.x;
    if (i < BATCH * PRED) {
        int b = i / PRED;
        out[i] = ws[OFF_ACC + i] * (1.0f / NS) * ws[OFF_SCALE + b] + ws[OFF_LOC + b];
    }
}

// ---------------- launch ----------------
extern "C" void kernel_launch(void* const* d_in, const int* in_sizes, int n_in,
                              void* d_out, int out_size, void* d_ws, size_t ws_size,
                              hipStream_t stream) {
    const float* targets = (const float*)d_in[0];
    const float* w_ih0 = (const float*)d_in[1];
    const float* w_hh0 = (const float*)d_in[2];
    const float* b_ih0 = (const float*)d_in[3];
    const float* b_hh0 = (const float*)d_in[4];
    const float* w_ih1 = (const float*)d_in[5];
    const float* w_hh1 = (const float*)d_in[6];
    const float* b_ih1 = (const float*)d_in[7];
    const float* b_hh1 = (const float*)d_in[8];
    const float* w_mu = (const float*)d_in[9];
    const float* b_mu = (const float*)d_in[10];
    const float* w_sigma = (const float*)d_in[11];
    const float* b_sigma = (const float*)d_in[12];
    const float* eps = (const float*)d_in[13];
    float* ws = (float*)d_ws;
    float* out = (float*)d_out;

    hipLaunchKernelGGL(prep_weights, dim3(1024), dim3(256), 0, stream,
                       w_ih0, w_hh0, b_ih0, b_hh0, w_ih1, w_hh1, b_ih1, b_hh1, ws);
    hipLaunchKernelGGL(prep_norm, dim3(BATCH), dim3(256), 0, stream, targets, ws);
    hipLaunchKernelGGL(encoder_kernel, dim3(256), dim3(ENC_T), 0, stream, ws);
    hipLaunchKernelGGL(decoder_kernel, dim3(GROWS / RDEC), dim3(256), 0, stream,
                       ws, w_mu, b_mu, w_sigma, b_sigma, eps, ws);
    hipLaunchKernelGGL(finalize_kernel, dim3((BATCH * PRED + 255) / 256), dim3(256), 0,
                       stream, ws, out);
}

// Round 7
// 9991.078 us; speedup vs baseline: 16.2608x; 16.2608x over previous
//
#include <hip/hip_runtime.h>
#include <math.h>

// ---------------- problem constants ----------------
#define BATCH 256
#define TLEN  519          // W + MAXLAG
#define WIN   512
#define HID   256
#define PRED  24
#define NS    100
#define NLAG  7
#define GROWS (BATCH * NS) // 25600 decoder rows

// ---------------- workspace layout (float/uint offsets) ----------------
#define OFF_SCALED 0
#define OFF_LOC    132864
#define OFF_SCALE  133120
#define OFF_WIH0   133376   // fp32 [f][j][q], f<7  (encoder lag weights)
#define OFF_WHH0H  140544   // half2 [p][j][q], p<128 (encoder)
#define OFF_WCAT1H 271616   // half2 [p][j][q], p<256 (encoder, ih1|hh1)
#define OFF_B0     533760   // fp32 combined b_ih0+b_hh0, [j][q]
#define OFF_B1     534784
#define OFF_BN0    535808   // fp32 bias by MFMA col n (layer0)
#define OFF_BN1    536832
#define OFF_F0     537856   // fp16 B-fragments layer0: 9 ks x 64 nt x 64 lane x 8
#define OFF_F1     685312   // fp16 B-fragments layer1: 16 ks x 64 nt x 64 lane x 8
#define OFF_EH0    947456   // encoder final states fp32 [b][j]
#define OFF_EC0    1012992
#define OFF_EH1    1078528
#define OFF_EC1    1144064
#define OFF_ACC    1209600  // sample accumulators [b][p]
#define WS_FLOATS  1215744  // 4.86 MB

// ---------------- helpers ----------------
typedef _Float16 h2_t  __attribute__((ext_vector_type(2)));
typedef _Float16 half8 __attribute__((ext_vector_type(8)));
typedef float    f32x4 __attribute__((ext_vector_type(4)));

__device__ __forceinline__ float sigm(float x) { return 1.0f / (1.0f + __expf(-x)); }
__device__ __forceinline__ float ftanh(float x) {
    float e = __expf(2.0f * x);
    return 1.0f - 2.0f / (e + 1.0f);
}
__device__ __forceinline__ float softplus(float x) {
    return (x > 15.0f) ? x : log1pf(__expf(x));
}
__device__ __forceinline__ void fma4(float4& a, const float4 w, const float x) {
    a.x = fmaf(w.x, x, a.x);
    a.y = fmaf(w.y, x, a.y);
    a.z = fmaf(w.z, x, a.z);
    a.w = fmaf(w.w, x, a.w);
}
__device__ __forceinline__ float dot2(unsigned int h, unsigned int w, float acc) {
    return __builtin_amdgcn_fdot2(__builtin_bit_cast(h2_t, h),
                                  __builtin_bit_cast(h2_t, w), acc, false);
}
__device__ __forceinline__ void dot2x4(float4& a, const unsigned int h, const uint4 w) {
    a.x = dot2(h, w.x, a.x);
    a.y = dot2(h, w.y, a.y);
    a.z = dot2(h, w.z, a.z);
    a.w = dot2(h, w.w, a.w);
}
__device__ __forceinline__ unsigned int packh2(float a, float b) {
    h2_t h;
    h.x = (_Float16)a;
    h.y = (_Float16)b;
    return __builtin_bit_cast(unsigned int, h);
}
__device__ __forceinline__ unsigned short hbits(float v) {
    return __builtin_bit_cast(unsigned short, (_Float16)v);
}

// ---------------- kernel 1: repack weights ----------------
__global__ __launch_bounds__(256) void prep_weights(
    const float* __restrict__ w_ih0, const float* __restrict__ w_hh0,
    const float* __restrict__ b_ih0, const float* __restrict__ b_hh0,
    const float* __restrict__ w_ih1, const float* __restrict__ w_hh1,
    const float* __restrict__ b_ih1, const float* __restrict__ b_hh1,
    float* __restrict__ ws) {
    int id = blockIdx.x * blockDim.x + threadIdx.x;   // grid covers 262144
    unsigned int* wsu = (unsigned int*)ws;
    // ---- encoder layouts ----
    {
        int g4 = id & 1023;
        int jj = g4 >> 2, q = g4 & 3;
        int grow = q * HID + jj;
        int p = id >> 10;
        int k0 = 2 * p;
        float v0, v1;
        if (k0 < 256) { v0 = w_ih1[grow * HID + k0];       v1 = w_ih1[grow * HID + k0 + 1]; }
        else          { v0 = w_hh1[grow * HID + k0 - 256]; v1 = w_hh1[grow * HID + k0 - 255]; }
        wsu[OFF_WCAT1H + id] = packh2(v0, v1);
        if (id < 131072) {
            wsu[OFF_WHH0H + id] = packh2(w_hh0[grow * HID + 2 * p], w_hh0[grow * HID + 2 * p + 1]);
        }
        if (id < 7168) {
            int f = id >> 10;
            ws[OFF_WIH0 + id] = w_ih0[grow * NLAG + f];
        }
        if (id < 1024) {
            ws[OFF_B0 + id] = b_ih0[grow] + b_hh0[grow];
            ws[OFF_B1 + id] = b_ih1[grow] + b_hh1[grow];
        }
    }
    // ---- decoder biases by MFMA col ----
    if (id < 2048) {
        int n = id & 1023;
        int w = n >> 8, u = (n >> 2) & 63, q = n & 3;
        int grow = q * HID + w * 64 + u;
        if (id < 1024) ws[OFF_BN0 + n] = b_ih0[grow] + b_hh0[grow];
        else           ws[OFF_BN1 + n] = b_ih1[grow] + b_hh1[grow];
    }
    // ---- F0 fragments: 9 ks (ks0 = lag block) ----
    if (id < 36864) {
        int ks = id / 4096, rem = id % 4096, nt = rem >> 6, l = rem & 63;
        int n = nt * 16 + (l & 15);
        int w = n >> 8, u = (n >> 2) & 63, q = n & 3;
        int grow = q * HID + w * 64 + u;
        int kbase = (l >> 4) * 8;
        unsigned short h8[8];
        #pragma unroll
        for (int i = 0; i < 8; ++i) {
            float v;
            if (ks == 0) { int k = kbase + i; v = (k < NLAG) ? w_ih0[grow * NLAG + k] : 0.0f; }
            else         { int kk = (ks - 1) * 32 + kbase + i; v = w_hh0[grow * HID + kk]; }
            h8[i] = hbits(v);
        }
        uint4 o;
        o.x = (unsigned int)h8[0] | ((unsigned int)h8[1] << 16);
        o.y = (unsigned int)h8[2] | ((unsigned int)h8[3] << 16);
        o.z = (unsigned int)h8[4] | ((unsigned int)h8[5] << 16);
        o.w = (unsigned int)h8[6] | ((unsigned int)h8[7] << 16);
        ((uint4*)(ws + OFF_F0))[id] = o;
    }
    // ---- F1 fragments: 16 ks ----
    if (id < 65536) {
        int ks = id >> 12, rem = id & 4095, nt = rem >> 6, l = rem & 63;
        int n = nt * 16 + (l & 15);
        int w = n >> 8, u = (n >> 2) & 63, q = n & 3;
        int grow = q * HID + w * 64 + u;
        int kbase = (l >> 4) * 8;
        unsigned short h8[8];
        #pragma unroll
        for (int i = 0; i < 8; ++i) {
            int kk = ks * 32 + kbase + i;
            float v = (kk < 256) ? w_ih1[grow * HID + kk] : w_hh1[grow * HID + kk - 256];
            h8[i] = hbits(v);
        }
        uint4 o;
        o.x = (unsigned int)h8[0] | ((unsigned int)h8[1] << 16);
        o.y = (unsigned int)h8[2] | ((unsigned int)h8[3] << 16);
        o.z = (unsigned int)h8[4] | ((unsigned int)h8[5] << 16);
        o.w = (unsigned int)h8[6] | ((unsigned int)h8[7] << 16);
        ((uint4*)(ws + OFF_F1))[id] = o;
    }
}

// ---------------- kernel 2: normalize + zero accumulators ----------------
__global__ __launch_bounds__(256) void prep_norm(const float* __restrict__ x,
                                                 float* __restrict__ ws) {
    const int b = blockIdx.x, j = threadIdx.x;
    const float* row = x + b * TLEN;
    float s = 0.0f, s2 = 0.0f;
    for (int t = j; t < WIN; t += 256) {
        float v = row[NLAG + t];
        s += v;
        s2 = fmaf(v, v, s2);
    }
    #pragma unroll
    for (int off = 32; off > 0; off >>= 1) {
        s  += __shfl_down(s, off, 64);
        s2 += __shfl_down(s2, off, 64);
    }
    __shared__ float rs[4], rs2[4];
    __shared__ float sh_loc, sh_scale;
    int wave = j >> 6, lane = j & 63;
    if (lane == 0) { rs[wave] = s; rs2[wave] = s2; }
    __syncthreads();
    if (j == 0) {
        float S = rs[0] + rs[1] + rs[2] + rs[3];
        float S2 = rs2[0] + rs2[1] + rs2[2] + rs2[3];
        float mean = S * (1.0f / WIN);
        float var = S2 * (1.0f / WIN) - mean * mean;
        float sd = sqrtf(fmaxf(var, 0.0f));
        if (sd < 1e-10f) sd = 1.0f;
        sh_loc = mean; sh_scale = sd;
        ws[OFF_LOC + b] = mean;
        ws[OFF_SCALE + b] = sd;
    }
    __syncthreads();
    float loc = sh_loc, inv = 1.0f / sh_scale;
    for (int t = j; t < TLEN; t += 256) {
        ws[OFF_SCALED + b * TLEN + t] = (row[t] - loc) * inv;
    }
    if (j < PRED) ws[OFF_ACC + b * PRED + j] = 0.0f;
}

// ---------------- kernel 3: encoder (512 sequential steps) ----------------
// r5-verified structure: 128 blocks x 1024 threads (16 waves = 4/SIMD),
// 2 rows/block, 4-way IN-BLOCK k-split. 11.9 us/step measured = the per-CU
// L1<-L2 BW wall for the 1.57 MB/step fp16 weight stream. Cross-block
// alternatives are ruled out (r6: ~90 us per cross-XCD flag round).
#define ENC_T 1024
__global__ __launch_bounds__(ENC_T) void encoder_kernel(const float* __restrict__ wsr,
                                                        float* __restrict__ wsw) {
    const int tid = threadIdx.x;
    const int j  = tid & 255;      // unit
    const int kq = tid >> 8;       // k-quarter (0..3)
    const int bb = blockIdx.x;     // 0..127
    __shared__ unsigned int h0p[2][128], h1p[2][128];   // half2-packed h per row
    __shared__ float4 pgs[2][4][256];                   // [row][kq][unit]
    __shared__ float4 wlag[NLAG * 256];                 // lag weights (28 KB)
    __shared__ float xs[2][NLAG];
    float c0[2] = {0.0f, 0.0f}, c1[2] = {0.0f, 0.0f};

    for (int i = tid; i < NLAG * 256; i += ENC_T)
        wlag[i] = ((const float4*)(wsr + OFF_WIH0))[i];
    if (tid < 128) { h0p[0][tid] = 0u; h0p[1][tid] = 0u; h1p[0][tid] = 0u; h1p[1][tid] = 0u; }

    const uint4* W0 = (const uint4*)((const unsigned int*)wsr + OFF_WHH0H);
    const uint4* W1 = (const uint4*)((const unsigned int*)wsr + OFF_WCAT1H);
    float4 bv0 = {0, 0, 0, 0}, bv1 = {0, 0, 0, 0};
    if (kq == 0) {
        bv0 = ((const float4*)(wsr + OFF_B0))[j];
        bv1 = ((const float4*)(wsr + OFF_B1))[j];
    }
    const float* sc0 = wsr + OFF_SCALED + (bb * 2 + 0) * TLEN;
    const float* sc1 = wsr + OFF_SCALED + (bb * 2 + 1) * TLEN;
    __syncthreads();

    for (int t = 0; t < WIN; ++t) {
        if (tid < 2 * NLAG) {
            int r = tid / NLAG, f = tid % NLAG;
            xs[r][f] = (r ? sc1 : sc0)[t + 6 - f];
        }
        // ---- L0 partials: 32 k-pairs per quarter ----
        {
            float4 a0 = {0, 0, 0, 0}, a1 = {0, 0, 0, 0};
            const uint4* Wp = W0 + (kq * 32) * 256 + j;
            const unsigned int* hp0 = &h0p[0][kq * 32];
            const unsigned int* hp1 = &h0p[1][kq * 32];
            #pragma unroll 4
            for (int p = 0; p < 32; ++p) {
                uint4 w = Wp[p * 256];
                dot2x4(a0, hp0[p], w);
                dot2x4(a1, hp1[p], w);
            }
            pgs[0][kq][j] = a0;
            pgs[1][kq][j] = a1;
        }
        __syncthreads();   // [A] pgs + xs ready; all L0 reads of h0p done
        if (kq == 0) {
            #pragma unroll
            for (int r = 0; r < 2; ++r) {
                float4 a = bv0;
                #pragma unroll
                for (int f = 0; f < NLAG; ++f) fma4(a, wlag[f * 256 + j], xs[r][f]);
                #pragma unroll
                for (int h = 0; h < 4; ++h) {
                    float4 p = pgs[r][h][j];
                    a.x += p.x; a.y += p.y; a.z += p.z; a.w += p.w;
                }
                c0[r] = sigm(a.y) * c0[r] + sigm(a.x) * ftanh(a.z);
                ((_Float16*)&h0p[r][0])[j] = (_Float16)(sigm(a.w) * ftanh(c0[r]));
            }
        }
        __syncthreads();   // [B] h0p(t) visible
        // ---- L1 partials: 64 k-pairs per quarter over cat(h0,h1) ----
        {
            float4 a0 = {0, 0, 0, 0}, a1 = {0, 0, 0, 0};
            const uint4* Wp = W1 + (kq * 64) * 256 + j;
            const unsigned int* hp0 = (kq < 2) ? &h0p[0][(kq & 1) * 64] : &h1p[0][(kq & 1) * 64];
            const unsigned int* hp1 = (kq < 2) ? &h0p[1][(kq & 1) * 64] : &h1p[1][(kq & 1) * 64];
            #pragma unroll 4
            for (int p = 0; p < 64; ++p) {
                uint4 w = Wp[p * 256];
                dot2x4(a0, hp0[p], w);
                dot2x4(a1, hp1[p], w);
            }
            pgs[0][kq][j] = a0;
            pgs[1][kq][j] = a1;
        }
        __syncthreads();   // [C] pgs ready; all L1 reads of h1p done
        if (kq == 0) {
            #pragma unroll
            for (int r = 0; r < 2; ++r) {
                float4 g = bv1;
                #pragma unroll
                for (int h = 0; h < 4; ++h) {
                    float4 p = pgs[r][h][j];
                    g.x += p.x; g.y += p.y; g.z += p.z; g.w += p.w;
                }
                c1[r] = sigm(g.y) * c1[r] + sigm(g.x) * ftanh(g.z);
                ((_Float16*)&h1p[r][0])[j] = (_Float16)(sigm(g.w) * ftanh(c1[r]));
            }
        }
        __syncthreads();   // [D] h1p(t) visible; pgs safe to overwrite
    }
    if (kq == 0) {
        #pragma unroll
        for (int r = 0; r < 2; ++r) {
            int b = bb * 2 + r;
            wsw[OFF_EH0 + b * HID + j] = (float)((_Float16*)&h0p[r][0])[j];
            wsw[OFF_EC0 + b * HID + j] = c0[r];
            wsw[OFF_EH1 + b * HID + j] = (float)((_Float16*)&h1p[r][0])[j];
            wsw[OFF_EC1 + b * HID + j] = c1[r];
        }
    }
}

// ---------------- kernel 4: MFMA decoder (r4-verified, RDEC=32) ----------------
// 32 rows/block, 800 blocks, VGPR 128 (no spill — r5's RDEC=64 spilled to
// scratch and thrashed L2). LDS 53 KB -> 2 blocks/CU.
#define RDEC 32
__global__ __launch_bounds__(256, 2) void decoder_kernel(
    const float* __restrict__ wsr,
    const float* __restrict__ w_mu, const float* __restrict__ b_mu,
    const float* __restrict__ w_sigma, const float* __restrict__ b_sigma,
    const float* __restrict__ eps, float* __restrict__ wsw) {
    const int j = threadIdx.x, lane = j & 63, wv = j >> 6;
    const int gr0 = blockIdx.x * RDEC;
    const int m16 = lane & 15, q16 = lane >> 4;
    __shared__ _Float16 hA[2][RDEC][264];   // [layer][row][unit], pad to 264
    __shared__ _Float16 xlag[RDEC][32];     // lag A-tile (k 0..6 live, rest 0)
    __shared__ float scr[4][16][68];        // per-wave D transpose scratch

    const uint4* F0 = (const uint4*)(wsr + OFF_F0);
    const uint4* F1 = (const uint4*)(wsr + OFF_F1);
    const float* bn0 = wsr + OFF_BN0;
    const float* bn1 = wsr + OFF_BN1;

    float c0r[8][4], c1r[8][4];
    for (int r = 0; r < RDEC; ++r) {
        int b = (gr0 + r) / NS;
        hA[0][r][j] = (_Float16)wsr[OFF_EH0 + b * HID + j];
        hA[1][r][j] = (_Float16)wsr[OFF_EH1 + b * HID + j];
    }
    { int r = j >> 3, p = j & 7;
      hA[0][r][256 + p] = (_Float16)0.0f; hA[1][r][256 + p] = (_Float16)0.0f; }
    #pragma unroll
    for (int it = 0; it < 4; ++it) {
        int idx = j + 256 * it;
        int r = idx >> 5, k = idx & 31;
        int b = (gr0 + r) / NS;
        xlag[r][k] = (k < NLAG) ? (_Float16)wsr[OFF_SCALED + b * TLEN + WIN + 6 - k]
                                : (_Float16)0.0f;
    }
    #pragma unroll
    for (int Q = 0; Q < 4; ++Q)
        #pragma unroll
        for (int mt = 0; mt < 2; ++mt) {
            int t2 = Q * 2 + mt;
            int b = (gr0 + mt * 16 + m16) / NS;
            #pragma unroll
            for (int i = 0; i < 4; ++i) {
                int jg = wv * 64 + Q * 16 + q16 * 4 + i;
                c0r[t2][i] = wsr[OFF_EC0 + b * HID + jg];
                c1r[t2][i] = wsr[OFF_EC1 + b * HID + jg];
            }
        }
    __syncthreads();

    float* accg = wsw + OFF_ACC;
    for (int st = 0; st < PRED; ++st) {
        uint2 hnew[8];
        // ================= layer 0 =================
        #pragma unroll 1
        for (int Q = 0; Q < 4; ++Q) {
            f32x4 acc[2][4];
            #pragma unroll
            for (int t = 0; t < 4; ++t) {
                float bb = bn0[wv * 256 + Q * 64 + t * 16 + m16];
                acc[0][t] = (f32x4){bb, bb, bb, bb};
                acc[1][t] = acc[0][t];
            }
            #pragma unroll
            for (int ks = 0; ks < 9; ++ks) {
                uint4 bw[4];
                #pragma unroll
                for (int t = 0; t < 4; ++t)
                    bw[t] = F0[(ks * 64 + wv * 16 + Q * 4 + t) * 64 + lane];
                #pragma unroll
                for (int mt = 0; mt < 2; ++mt) {
                    const _Float16* ap = (ks == 0)
                        ? &xlag[mt * 16 + m16][q16 * 8]
                        : &hA[0][mt * 16 + m16][(ks - 1) * 32 + q16 * 8];
                    half8 av = *(const half8*)ap;
                    #pragma unroll
                    for (int t = 0; t < 4; ++t)
                        acc[mt][t] = __builtin_amdgcn_mfma_f32_16x16x32_f16(
                            av, __builtin_bit_cast(half8, bw[t]), acc[mt][t], 0, 0, 0);
                }
            }
            #pragma unroll
            for (int mt = 0; mt < 2; ++mt) {
                #pragma unroll
                for (int t = 0; t < 4; ++t)
                    #pragma unroll
                    for (int rg = 0; rg < 4; ++rg)
                        scr[wv][q16 * 4 + rg][t * 16 + m16] = acc[mt][t][rg];
                __builtin_amdgcn_wave_barrier();
                int t2 = Q * 2 + mt;
                float hv[4];
                #pragma unroll
                for (int i = 0; i < 4; ++i) {
                    float4 g = *(const float4*)&scr[wv][m16][(q16 * 4 + i) * 4];
                    float c = sigm(g.y) * c0r[t2][i] + sigm(g.x) * ftanh(g.z);
                    c0r[t2][i] = c;
                    hv[i] = sigm(g.w) * ftanh(c);
                }
                __builtin_amdgcn_wave_barrier();
                hnew[t2] = make_uint2(packh2(hv[0], hv[1]), packh2(hv[2], hv[3]));
            }
        }
        __syncthreads();   // all L0 reads of hA[0]/xlag done
        #pragma unroll
        for (int Q = 0; Q < 4; ++Q)
            #pragma unroll
            for (int mt = 0; mt < 2; ++mt)
                *(uint2*)&hA[0][mt * 16 + m16][wv * 64 + Q * 16 + q16 * 4] = hnew[Q * 2 + mt];
        __syncthreads();   // hA[0] now h0(t)
        // ================= layer 1 =================
        #pragma unroll 1
        for (int Q = 0; Q < 4; ++Q) {
            f32x4 acc[2][4];
            #pragma unroll
            for (int t = 0; t < 4; ++t) {
                float bb = bn1[wv * 256 + Q * 64 + t * 16 + m16];
                acc[0][t] = (f32x4){bb, bb, bb, bb};
                acc[1][t] = acc[0][t];
            }
            #pragma unroll
            for (int ks = 0; ks < 16; ++ks) {
                uint4 bw[4];
                #pragma unroll
                for (int t = 0; t < 4; ++t)
                    bw[t] = F1[(ks * 64 + wv * 16 + Q * 4 + t) * 64 + lane];
                #pragma unroll
                for (int mt = 0; mt < 2; ++mt) {
                    const _Float16* ap = (ks < 8)
                        ? &hA[0][mt * 16 + m16][ks * 32 + q16 * 8]
                        : &hA[1][mt * 16 + m16][(ks - 8) * 32 + q16 * 8];
                    half8 av = *(const half8*)ap;
                    #pragma unroll
                    for (int t = 0; t < 4; ++t)
                        acc[mt][t] = __builtin_amdgcn_mfma_f32_16x16x32_f16(
                            av, __builtin_bit_cast(half8, bw[t]), acc[mt][t], 0, 0, 0);
                }
            }
            #pragma unroll
            for (int mt = 0; mt < 2; ++mt) {
                #pragma unroll
                for (int t = 0; t < 4; ++t)
                    #pragma unroll
                    for (int rg = 0; rg < 4; ++rg)
                        scr[wv][q16 * 4 + rg][t * 16 + m16] = acc[mt][t][rg];
                __builtin_amdgcn_wave_barrier();
                int t2 = Q * 2 + mt;
                float hv[4];
                #pragma unroll
                for (int i = 0; i < 4; ++i) {
                    float4 g = *(const float4*)&scr[wv][m16][(q16 * 4 + i) * 4];
                    float c = sigm(g.y) * c1r[t2][i] + sigm(g.x) * ftanh(g.z);
                    c1r[t2][i] = c;
                    hv[i] = sigm(g.w) * ftanh(c);
                }
                __builtin_amdgcn_wave_barrier();
                hnew[t2] = make_uint2(packh2(hv[0], hv[1]), packh2(hv[2], hv[3]));
            }
        }
        __syncthreads();   // all L1 reads of hA done
        #pragma unroll
        for (int Q = 0; Q < 4; ++Q)
            #pragma unroll
            for (int mt = 0; mt < 2; ++mt)
                *(uint2*)&hA[1][mt * 16 + m16][wv * 64 + Q * 16 + q16 * 4] = hnew[Q * 2 + mt];
        __syncthreads();   // hA[1] now h1(t)
        // ================= mu / sigma / sample =================
        #pragma unroll 1
        for (int it = 0; it < 8; ++it) {
            int rr = wv + it * 4;
            uint2 hu = *(const uint2*)&hA[1][rr][lane * 4];
            h2_t p0 = __builtin_bit_cast(h2_t, hu.x);
            h2_t p1 = __builtin_bit_cast(h2_t, hu.y);
            float4 wm = *(const float4*)&w_mu[lane * 4];
            float4 wsg = *(const float4*)&w_sigma[lane * 4];
            float h0f = (float)p0.x, h1f = (float)p0.y, h2f = (float)p1.x, h3f = (float)p1.y;
            float sm = h0f * wm.x + h1f * wm.y + h2f * wm.z + h3f * wm.w;
            float ss = h0f * wsg.x + h1f * wsg.y + h2f * wsg.z + h3f * wsg.w;
            #pragma unroll
            for (int off = 32; off > 0; off >>= 1) {
                sm += __shfl_down(sm, off, 64);
                ss += __shfl_down(ss, off, 64);
            }
            if (lane == 0) {
                float mu = sm + b_mu[0];
                float sg = softplus(ss + b_sigma[0]);
                int gr = gr0 + rr;
                float smp = fmaf(sg, eps[st * GROWS + gr], mu);
                atomicAdd(&accg[(gr / NS) * PRED + st], smp);
                #pragma unroll
                for (int f = NLAG - 1; f >= 1; --f) xlag[rr][f] = xlag[rr][f - 1];
                xlag[rr][0] = (_Float16)smp;
            }
        }
        __syncthreads();   // xlag(t+1) visible
    }
}

// ---------------- kernel 5: finalize ----------------
__global__ __launch_bounds__(256) void finalize_kernel(const float* __restrict__ ws,
                                                       float* __restrict__ out) {
    int i = blockIdx.x * blockDim.x + threadIdx.x;
    if (i < BATCH * PRED) {
        int b = i / PRED;
        out[i] = ws[OFF_ACC + i] * (1.0f / NS) * ws[OFF_SCALE + b] + ws[OFF_LOC + b];
    }
}

// ---------------- launch ----------------
extern "C" void kernel_launch(void* const* d_in, const int* in_sizes, int n_in,
                              void* d_out, int out_size, void* d_ws, size_t ws_size,
                              hipStream_t stream) {
    const float* targets = (const float*)d_in[0];
    const float* w_ih0 = (const float*)d_in[1];
    const float* w_hh0 = (const float*)d_in[2];
    const float* b_ih0 = (const float*)d_in[3];
    const float* b_hh0 = (const float*)d_in[4];
    const float* w_ih1 = (const float*)d_in[5];
    const float* w_hh1 = (const float*)d_in[6];
    const float* b_ih1 = (const float*)d_in[7];
    const float* b_hh1 = (const float*)d_in[8];
    const float* w_mu = (const float*)d_in[9];
    const float* b_mu = (const float*)d_in[10];
    const float* w_sigma = (const float*)d_in[11];
    const float* b_sigma = (const float*)d_in[12];
    const float* eps = (const float*)d_in[13];
    float* ws = (float*)d_ws;
    float* out = (float*)d_out;

    hipLaunchKernelGGL(prep_weights, dim3(1024), dim3(256), 0, stream,
                       w_ih0, w_hh0, b_ih0, b_hh0, w_ih1, w_hh1, b_ih1, b_hh1, ws);
    hipLaunchKernelGGL(prep_norm, dim3(BATCH), dim3(256), 0, stream, targets, ws);
    hipLaunchKernelGGL(encoder_kernel, dim3(128), dim3(ENC_T), 0, stream, ws, ws);
    hipLaunchKernelGGL(decoder_kernel, dim3(GROWS / RDEC), dim3(256), 0, stream,
                       ws, w_mu, b_mu, w_sigma, b_sigma, eps, ws);
    hipLaunchKernelGGL(finalize_kernel, dim3((BATCH * PRED + 255) / 256), dim3(256), 0,
                       stream, ws, out);
}